// Round 9
// baseline (104.075 us; speedup 1.0000x reference)
//
#include <hip/hip_runtime.h>
#include <hip/hip_bf16.h>

// LocalFeatureAggregation: B=2, N=32768, K=16, CIN=8, COUT=64
// MFMA version 5. Block = 256 = 4 waves, zero barriers, wave-local LDS.
// vs v4: b3f (ATT weight fragments, 32 VGPRs) no longer persistent -- loaded
// per pair-loop from the L2-hot prepacked workspace (opaque-zero index stops
// LICM from rehoisting), and launch_bounds(256,3) targets 3 waves/SIMD.
// Round-5 lesson: (256,3) WITHOUT the register diet causes 80 MB scratch
// spill; WRITE_SIZE == 16384 KB is the no-spill tripwire.
// Grid = 2048 blocks x 2 iters x 16 points.

typedef __attribute__((ext_vector_type(8))) short short8v;
typedef __attribute__((ext_vector_type(4))) float float4v;

#define BN_INV 0.9999950000374997f
#define NFRAG 22
#define NSCAL 20

// cheap float->bf16, round-half-up (1-ulp-on-ties vs RNE; inputs finite)
__device__ __forceinline__ ushort f2bf(float f) {
    return (ushort)((__float_as_uint(f) + 0x8000u) >> 16);
}
// pack two: low half = bf16(a), high half = bf16(b)   (2 add + 1 perm)
__device__ __forceinline__ uint pk2(float a, float b) {
    return __builtin_amdgcn_perm(__float_as_uint(b) + 0x8000u,
                                 __float_as_uint(a) + 0x8000u, 0x07060302u);
}

__device__ __forceinline__ ushort f2bf_rne(float f) {
    __hip_bfloat16 h = __float2bfloat16(f);
    return __builtin_bit_cast(ushort, h);
}

// ---- setup: pack per-lane MFMA B-fragments + scale/shift into d_ws ----
// layout: [NFRAG][64] x 16B fragments, then [NSCAL][64] x f32.
// frag order: 0 b1f0, 1 b1f1, 2-5 b2f[t], 6-13 b3f[2t+h], 14-21 pbf[2t+h].
__global__ __launch_bounds__(256)
void lfa_pack(const float* __restrict__ wm1, const float* __restrict__ wm2,
              const float* __restrict__ watt, const float* __restrict__ wp,
              const float* __restrict__ gm1, const float* __restrict__ bm1,
              const float* __restrict__ gm2, const float* __restrict__ bm2,
              const float* __restrict__ gp,  const float* __restrict__ bp,
              ushort* __restrict__ ws)
{
    const int t = blockIdx.x * 256 + threadIdx.x;
    if (t < NFRAG * 64) {
        const int f = t >> 6, l = t & 63, r = l & 15, Q = l >> 4;
        short8v v;
        #pragma unroll
        for (int j = 0; j < 8; ++j) {
            const int k = 8 * Q + j;
            float x;
            if (f == 0)      x = (k < 24) ? wm1[r * 24 + k] : 0.f;
            else if (f == 1) x = (k < 24) ? wm1[(16 + r) * 24 + k] : 0.f;
            else if (f < 6)  { int tt = f - 2;  x = wm2[(16 * tt + r) * 32 + k]; }
            else if (f < 14) { int i = f - 6,  tt = i >> 1, h = i & 1;
                               x = watt[(16 * tt + r) * 64 + 32 * h + k]; }
            else             { int i = f - 14, tt = i >> 1, h = i & 1;
                               x = wp[(16 * tt + r) * 64 + 32 * h + k]; }
            v[j] = (short)f2bf_rne(x);
        }
        ((short8v*)ws)[t] = v;
    } else if (t < NFRAG * 64 + NSCAL * 64) {
        const int i = t - NFRAG * 64;
        const int fld = i >> 6, l = i & 63, r = l & 15;
        float x;
        if (fld == 0)      x = gm1[r] * BN_INV;
        else if (fld == 1) x = bm1[r];
        else if (fld == 2) x = gm1[16 + r] * BN_INV;
        else if (fld == 3) x = bm1[16 + r];
        else if (fld < 8)  x = gm2[16 * (fld - 4) + r] * BN_INV;
        else if (fld < 12) x = bm2[16 * (fld - 8) + r];
        else if (fld < 16) x = gp[16 * (fld - 12) + r] * BN_INV;
        else               x = bp[16 * (fld - 16) + r];
        ((float*)(ws + NFRAG * 64 * 8))[i] = x;
    }
}

__global__ __launch_bounds__(256, 3)
void lfa_kernel(const float* __restrict__ coords,
                const float* __restrict__ feats,
                const int*   __restrict__ nidx,
                const float* __restrict__ w1, const float* __restrict__ g1, const float* __restrict__ b1,
                const float* __restrict__ w2, const float* __restrict__ g2, const float* __restrict__ b2,
                const ushort* __restrict__ fw,
                float* __restrict__ out)
{
    // per-wave slices: X1 4pt x 16 rows x 40 ushorts (pt stride 648)
    //                  X2 2 tiles x 16 x 40 (X3B aliases this, stride 72)
    //                  X3 16 x 76 ; PL aliases X1 tile 0
    __shared__ __align__(16) ushort sX1[4 * 2592];   // 20736 B
    __shared__ __align__(16) ushort sX2[4 * 1280];   // 10240 B
    __shared__ __align__(16) ushort sX3[4 * 1216];   //  9728 B => 40704 B

    const int tid = threadIdx.x;
    const int wv  = tid >> 6;
    const int l   = tid & 63;
    const int r   = l & 15;
    const int Q   = l >> 4;

    // ---- persistent fragments (b1/b2 only; b3 reloaded per pair-loop,
    //      pool fragments reloaded per wave-iter at the epilogue) ----
    const short8v* FR = (const short8v*)fw;
    const float*   SC = (const float*)(fw + NFRAG * 64 * 8);
    const short8v b1f0 = FR[0 * 64 + l];
    const short8v b1f1 = FR[1 * 64 + l];
    short8v b2f[4];
    #pragma unroll
    for (int t = 0; t < 4; ++t) b2f[t] = FR[(2 + t) * 64 + l];

    const float sm1a = SC[0 * 64 + l], tm1a = SC[1 * 64 + l];
    const float sm1b = SC[2 * 64 + l], tm1b = SC[3 * 64 + l];
    float sm2[4], tm2[4];
    #pragma unroll
    for (int t = 0; t < 4; ++t) {
        sm2[t] = SC[(4 + t) * 64 + l];  tm2[t] = SC[(8 + t) * 64 + l];
    }

    ushort* X1  = &sX1[wv * 2592];
    ushort* X2A = &sX2[wv * 1280];
    ushort* X2B = X2A + 640;
    ushort* X3A = &sX3[wv * 1216];
    ushort* X3B = X2A;            // 16 x 72, aliases dead X2A/X2B space
    ushort* PL  = X1;             // pooled rows (stride 76) alias X1 tile 0

    for (int it = 0; it < 2; ++it) {
        const int pt0 = blockIdx.x * 32 + it * 16 + wv * 4;

        // ===== LSE phase: lane = (point Q, neighbor r) =====
        {
            const int pt  = pt0 + Q;
            const int bb  = pt >> 15;
            const int nb  = nidx[pt0 * 16 + l];
            const int nbr = (bb << 15) + nb;

            const float cx = coords[pt * 3 + 0], cy = coords[pt * 3 + 1], cz = coords[pt * 3 + 2];
            const float rx = coords[nbr * 3 + 0] - cx;
            const float ry = coords[nbr * 3 + 1] - cy;
            const float rz = coords[nbr * 3 + 2] - cz;
            const float dd = sqrtf(rx * rx + ry * ry + rz * rz);
            float e4[4] = {rx, ry, rz, dd};

            float x24[24];
            {
                const float4* fp4 = (const float4*)(feats + nbr * 8);
                float4 f0 = fp4[0], f1 = fp4[1];
                x24[0] = f0.x; x24[1] = f0.y; x24[2] = f0.z; x24[3] = f0.w;
                x24[4] = f1.x; x24[5] = f1.y; x24[6] = f1.z; x24[7] = f1.w;
            }
            float h1[8];
            #pragma unroll
            for (int o = 0; o < 8; ++o) {
                float a = 0.f;
                #pragma unroll
                for (int i = 0; i < 4; ++i) a = fmaf(w1[o * 4 + i], e4[i], a);
                h1[o] = fmaxf(fmaf(a, g1[o] * BN_INV, b1[o]), 0.f);
            }
            #pragma unroll
            for (int o = 0; o < 16; ++o) {
                float a = 0.f;
                #pragma unroll
                for (int i = 0; i < 8; ++i) a = fmaf(w2[o * 8 + i], h1[i], a);
                x24[8 + o] = fmaxf(fmaf(a, g2[o] * BN_INV, b2[o]), 0.f);
            }
            uint4* row = (uint4*)&X1[Q * 648 + r * 40];
            row[0] = make_uint4(pk2(x24[0],  x24[1]),  pk2(x24[2],  x24[3]),
                                pk2(x24[4],  x24[5]),  pk2(x24[6],  x24[7]));
            row[1] = make_uint4(pk2(x24[8],  x24[9]),  pk2(x24[10], x24[11]),
                                pk2(x24[12], x24[13]), pk2(x24[14], x24[15]));
            row[2] = make_uint4(pk2(x24[16], x24[17]), pk2(x24[18], x24[19]),
                                pk2(x24[20], x24[21]), pk2(x24[22], x24[23]));
            row[3] = make_uint4(0u, 0u, 0u, 0u);
        }

        // ===== paired per-point MFMA chains (points 2pp, 2pp+1) =====
        const float4v z0 = {0.f, 0.f, 0.f, 0.f};
        #pragma unroll 1
        for (int pp = 0; pp < 2; ++pp) {
            ushort* X1A = X1 + (2 * pp) * 648;
            ushort* X1B = X1A + 648;
            const short8v a1A = *(const short8v*)&X1A[r * 40 + Q * 8];
            const short8v a1B = *(const short8v*)&X1B[r * 40 + Q * 8];
            const float4v d1aA = __builtin_amdgcn_mfma_f32_16x16x32_bf16(a1A, b1f0, z0, 0, 0, 0);
            const float4v d1bA = __builtin_amdgcn_mfma_f32_16x16x32_bf16(a1A, b1f1, z0, 0, 0, 0);
            const float4v d1aB = __builtin_amdgcn_mfma_f32_16x16x32_bf16(a1B, b1f0, z0, 0, 0, 0);
            const float4v d1bB = __builtin_amdgcn_mfma_f32_16x16x32_bf16(a1B, b1f1, z0, 0, 0, 0);
            #pragma unroll
            for (int q = 0; q < 4; ++q) {
                X2A[(4 * Q + q) * 40 + r]      = f2bf(fmaxf(fmaf(d1aA[q], sm1a, tm1a), 0.f));
                X2A[(4 * Q + q) * 40 + 16 + r] = f2bf(fmaxf(fmaf(d1bA[q], sm1b, tm1b), 0.f));
                X2B[(4 * Q + q) * 40 + r]      = f2bf(fmaxf(fmaf(d1aB[q], sm1a, tm1a), 0.f));
                X2B[(4 * Q + q) * 40 + 16 + r] = f2bf(fmaxf(fmaf(d1bB[q], sm1b, tm1b), 0.f));
            }
            const short8v a2A = *(const short8v*)&X2A[r * 40 + Q * 8];
            const short8v a2B = *(const short8v*)&X2B[r * 40 + Q * 8];
            float4v d2A[4], d2B[4];
            #pragma unroll
            for (int t = 0; t < 4; ++t) {
                d2A[t] = __builtin_amdgcn_mfma_f32_16x16x32_bf16(a2A, b2f[t], z0, 0, 0, 0);
                d2B[t] = __builtin_amdgcn_mfma_f32_16x16x32_bf16(a2B, b2f[t], z0, 0, 0, 0);
            }
            float xrA[4][4], xrB[4][4];
            #pragma unroll
            for (int t = 0; t < 4; ++t)
                #pragma unroll
                for (int q = 0; q < 4; ++q) {
                    xrA[t][q] = fmaxf(fmaf(d2A[t][q], sm2[t], tm2[t]), 0.f);
                    xrB[t][q] = fmaxf(fmaf(d2B[t][q], sm2[t], tm2[t]), 0.f);
                }

            // ---- ATT weight fragments: reloaded HERE each pair-loop (L2-hot,
            //      coalesced). Opaque zero keeps LICM from re-hoisting them into
            //      persistent registers; X3 fill below covers the load latency.
            int zi = 0;
            asm volatile("" : "+v"(zi));
            short8v b3f[8];
            #pragma unroll
            for (int i = 0; i < 8; ++i) b3f[i] = FR[(6 + i) * 64 + l + zi];

            // ---- fill both X3 tiles (X3B writes ordered after a2 reads) ----
            #pragma unroll
            for (int t = 0; t < 4; ++t)
                #pragma unroll
                for (int q = 0; q < 4; ++q) {
                    X3A[(4 * Q + q) * 76 + 16 * t + r] = f2bf(xrA[t][q]);
                    X3B[(4 * Q + q) * 72 + 16 * t + r] = f2bf(xrB[t][q]);
                }
            const short8v a3lA = *(const short8v*)&X3A[r * 76 + Q * 8];
            const short8v a3hA = *(const short8v*)&X3A[r * 76 + 32 + Q * 8];
            const short8v a3lB = *(const short8v*)&X3B[r * 72 + Q * 8];
            const short8v a3hB = *(const short8v*)&X3B[r * 72 + 32 + Q * 8];

            // ---- interleaved ATT + softmax for A and B ----
            float seA[4], snA[4], seB[4], snB[4];
            #pragma unroll
            for (int t = 0; t < 4; ++t) {
                float4v sA = __builtin_amdgcn_mfma_f32_16x16x32_bf16(a3lA, b3f[t * 2],     z0, 0, 0, 0);
                sA         = __builtin_amdgcn_mfma_f32_16x16x32_bf16(a3hA, b3f[t * 2 + 1], sA, 0, 0, 0);
                float4v sB = __builtin_amdgcn_mfma_f32_16x16x32_bf16(a3lB, b3f[t * 2],     z0, 0, 0, 0);
                sB         = __builtin_amdgcn_mfma_f32_16x16x32_bf16(a3hB, b3f[t * 2 + 1], sB, 0, 0, 0);
                float e0A = __expf(sA[0]), e1A = __expf(sA[1]);
                float e2A = __expf(sA[2]), e3A = __expf(sA[3]);
                float e0B = __expf(sB[0]), e1B = __expf(sB[1]);
                float e2B = __expf(sB[2]), e3B = __expf(sB[3]);
                seA[t] = (e0A + e1A) + (e2A + e3A);
                snA[t] = fmaf(e0A, xrA[t][0], e1A * xrA[t][1]) + fmaf(e2A, xrA[t][2], e3A * xrA[t][3]);
                seB[t] = (e0B + e1B) + (e2B + e3B);
                snB[t] = fmaf(e0B, xrB[t][0], e1B * xrB[t][1]) + fmaf(e2B, xrB[t][2], e3B * xrB[t][3]);
            }
            #pragma unroll
            for (int t = 0; t < 4; ++t) {
                seA[t] += __shfl_xor(seA[t], 16, 64);
                snA[t] += __shfl_xor(snA[t], 16, 64);
                seB[t] += __shfl_xor(seB[t], 16, 64);
                snB[t] += __shfl_xor(snB[t], 16, 64);
                seA[t] += __shfl_xor(seA[t], 32, 64);
                snA[t] += __shfl_xor(snA[t], 32, 64);
                seB[t] += __shfl_xor(seB[t], 32, 64);
                snB[t] += __shfl_xor(snB[t], 32, 64);
            }
            if (l < 16) {
                #pragma unroll
                for (int t = 0; t < 4; ++t) {
                    PL[(2 * pp) * 76 + 16 * t + l]     = f2bf(__fdividef(snA[t], seA[t]));
                    PL[(2 * pp + 1) * 76 + 16 * t + l] = f2bf(__fdividef(snB[t], seB[t]));
                }
            }
        }

        // ===== batched pool MFMA (fragments loaded fresh each wave-iter) =====
        short8v pbf[8];
        #pragma unroll
        for (int i = 0; i < 8; ++i) pbf[i] = FR[(14 + i) * 64 + l];
        float spv[4], tpv[4];
        #pragma unroll
        for (int t = 0; t < 4; ++t) {
            spv[t] = SC[(12 + t) * 64 + l]; tpv[t] = SC[(16 + t) * 64 + l];
        }
        const short8v apl0 = *(const short8v*)&PL[r * 76 + Q * 8];
        const short8v apl1 = *(const short8v*)&PL[r * 76 + 32 + Q * 8];
        float4v dp[4];
        #pragma unroll
        for (int t = 0; t < 4; ++t) {
            float4v d = __builtin_amdgcn_mfma_f32_16x16x32_bf16(apl0, pbf[t * 2],     z0, 0, 0, 0);
            d         = __builtin_amdgcn_mfma_f32_16x16x32_bf16(apl1, pbf[t * 2 + 1], d,  0, 0, 0);
            dp[t] = d;
        }
        if (l < 16) {
            #pragma unroll
            for (int q = 0; q < 4; ++q)
                #pragma unroll
                for (int t = 0; t < 4; ++t)
                    out[(pt0 + q) * 64 + 16 * t + l] =
                        fmaxf(fmaf(dp[t][q], spv[t], tpv[t]), 0.f);
        }
    }
}

extern "C" void kernel_launch(void* const* d_in, const int* in_sizes, int n_in,
                              void* d_out, int out_size, void* d_ws, size_t ws_size,
                              hipStream_t stream) {
    (void)in_sizes; (void)n_in; (void)ws_size; (void)out_size;
    const float* coords = (const float*)d_in[0];
    const float* feats  = (const float*)d_in[1];
    const int*   nidx   = (const int*)  d_in[2];
    const float* w1  = (const float*)d_in[3];
    const float* g1  = (const float*)d_in[4];
    const float* b1  = (const float*)d_in[5];
    const float* w2  = (const float*)d_in[6];
    const float* g2  = (const float*)d_in[7];
    const float* b2  = (const float*)d_in[8];
    const float* wm1 = (const float*)d_in[9];
    const float* gm1 = (const float*)d_in[10];
    const float* bm1 = (const float*)d_in[11];
    const float* wm2 = (const float*)d_in[12];
    const float* gm2 = (const float*)d_in[13];
    const float* bm2 = (const float*)d_in[14];
    const float* watt = (const float*)d_in[15];
    const float* wp  = (const float*)d_in[16];
    const float* gp  = (const float*)d_in[17];
    const float* bp  = (const float*)d_in[18];
    float* out = (float*)d_out;
    ushort* ws = (ushort*)d_ws;

    lfa_pack<<<dim3(11), dim3(256), 0, stream>>>(wm1, wm2, watt, wp,
                                                 gm1, bm1, gm2, bm2, gp, bp, ws);
    lfa_kernel<<<dim3(2048), dim3(256), 0, stream>>>(coords, feats, nidx,
                                                     w1, g1, b1, w2, g2, b2,
                                                     ws, out);
}

// Round 10
// 74.522 us; speedup vs baseline: 1.3966x; 1.3966x over previous
//
#include <hip/hip_runtime.h>
#include <hip/hip_bf16.h>

// LocalFeatureAggregation: B=2, N=32768, K=16, CIN=8, COUT=64
// MFMA version 6 = round-8 code with 1-WAVE BLOCKS (64 threads).
// Rationale: kernel has zero barriers and wave-local LDS; 4-wave blocks only
// quantize residency. 1-wave blocks: LDS 10176 B/block -> up to 15 blocks/CU.
// launch_bounds(64,2) keeps the proven (256,2)-equivalent 256-VGPR budget
// (both (256,3) attempts spilled: rounds 5 and 9).
// Grid = 8192 blocks x 2 iters x 8 points (4 points per wave-iter).

typedef __attribute__((ext_vector_type(8))) short short8v;
typedef __attribute__((ext_vector_type(4))) float float4v;

#define BN_INV 0.9999950000374997f
#define NFRAG 22
#define NSCAL 20

// cheap float->bf16, round-half-up (1-ulp-on-ties vs RNE; inputs finite)
__device__ __forceinline__ ushort f2bf(float f) {
    return (ushort)((__float_as_uint(f) + 0x8000u) >> 16);
}
// pack two: low half = bf16(a), high half = bf16(b)   (2 add + 1 perm)
__device__ __forceinline__ uint pk2(float a, float b) {
    return __builtin_amdgcn_perm(__float_as_uint(b) + 0x8000u,
                                 __float_as_uint(a) + 0x8000u, 0x07060302u);
}

__device__ __forceinline__ ushort f2bf_rne(float f) {
    __hip_bfloat16 h = __float2bfloat16(f);
    return __builtin_bit_cast(ushort, h);
}

// ---- setup: pack per-lane MFMA B-fragments + scale/shift into d_ws ----
// layout: [NFRAG][64] x 16B fragments, then [NSCAL][64] x f32.
// frag order: 0 b1f0, 1 b1f1, 2-5 b2f[t], 6-13 b3f[2t+h], 14-21 pbf[2t+h].
__global__ __launch_bounds__(256)
void lfa_pack(const float* __restrict__ wm1, const float* __restrict__ wm2,
              const float* __restrict__ watt, const float* __restrict__ wp,
              const float* __restrict__ gm1, const float* __restrict__ bm1,
              const float* __restrict__ gm2, const float* __restrict__ bm2,
              const float* __restrict__ gp,  const float* __restrict__ bp,
              ushort* __restrict__ ws)
{
    const int t = blockIdx.x * 256 + threadIdx.x;
    if (t < NFRAG * 64) {
        const int f = t >> 6, l = t & 63, r = l & 15, Q = l >> 4;
        short8v v;
        #pragma unroll
        for (int j = 0; j < 8; ++j) {
            const int k = 8 * Q + j;
            float x;
            if (f == 0)      x = (k < 24) ? wm1[r * 24 + k] : 0.f;
            else if (f == 1) x = (k < 24) ? wm1[(16 + r) * 24 + k] : 0.f;
            else if (f < 6)  { int tt = f - 2;  x = wm2[(16 * tt + r) * 32 + k]; }
            else if (f < 14) { int i = f - 6,  tt = i >> 1, h = i & 1;
                               x = watt[(16 * tt + r) * 64 + 32 * h + k]; }
            else             { int i = f - 14, tt = i >> 1, h = i & 1;
                               x = wp[(16 * tt + r) * 64 + 32 * h + k]; }
            v[j] = (short)f2bf_rne(x);
        }
        ((short8v*)ws)[t] = v;
    } else if (t < NFRAG * 64 + NSCAL * 64) {
        const int i = t - NFRAG * 64;
        const int fld = i >> 6, l = i & 63, r = l & 15;
        float x;
        if (fld == 0)      x = gm1[r] * BN_INV;
        else if (fld == 1) x = bm1[r];
        else if (fld == 2) x = gm1[16 + r] * BN_INV;
        else if (fld == 3) x = bm1[16 + r];
        else if (fld < 8)  x = gm2[16 * (fld - 4) + r] * BN_INV;
        else if (fld < 12) x = bm2[16 * (fld - 8) + r];
        else if (fld < 16) x = gp[16 * (fld - 12) + r] * BN_INV;
        else               x = bp[16 * (fld - 16) + r];
        ((float*)(ws + NFRAG * 64 * 8))[i] = x;
    }
}

__global__ __launch_bounds__(64, 2)
void lfa_kernel(const float* __restrict__ coords,
                const float* __restrict__ feats,
                const int*   __restrict__ nidx,
                const float* __restrict__ w1, const float* __restrict__ g1, const float* __restrict__ b1,
                const float* __restrict__ w2, const float* __restrict__ g2, const float* __restrict__ b2,
                const ushort* __restrict__ fw,
                float* __restrict__ out)
{
    // one wave per block: X1 4pt x 16 rows x 40 ushorts (pt stride 648)
    //                     X2 2 tiles x 16 x 40 (X3B aliases this, stride 72)
    //                     X3 16 x 76 ; PL aliases X1 tile 0   => 10176 B
    __shared__ __align__(16) ushort sX1[2592];
    __shared__ __align__(16) ushort sX2[1280];
    __shared__ __align__(16) ushort sX3[1216];

    const int l   = threadIdx.x & 63;
    const int r   = l & 15;
    const int Q   = l >> 4;

    // ---- persistent fragments (b1/b2/b3; pool stuff loaded at epilogue) ----
    const short8v* FR = (const short8v*)fw;
    const float*   SC = (const float*)(fw + NFRAG * 64 * 8);
    const short8v b1f0 = FR[0 * 64 + l];
    const short8v b1f1 = FR[1 * 64 + l];
    short8v b2f[4], b3f[8];
    #pragma unroll
    for (int t = 0; t < 4; ++t) b2f[t] = FR[(2 + t) * 64 + l];
    #pragma unroll
    for (int i = 0; i < 8; ++i) b3f[i] = FR[(6 + i) * 64 + l];

    const float sm1a = SC[0 * 64 + l], tm1a = SC[1 * 64 + l];
    const float sm1b = SC[2 * 64 + l], tm1b = SC[3 * 64 + l];
    float sm2[4], tm2[4];
    #pragma unroll
    for (int t = 0; t < 4; ++t) {
        sm2[t] = SC[(4 + t) * 64 + l];  tm2[t] = SC[(8 + t) * 64 + l];
    }

    ushort* X1  = sX1;
    ushort* X2A = sX2;
    ushort* X2B = X2A + 640;
    ushort* X3A = sX3;
    ushort* X3B = X2A;            // 16 x 72, aliases dead X2A/X2B space
    ushort* PL  = X1;             // pooled rows (stride 76) alias X1 tile 0

    for (int it = 0; it < 2; ++it) {
        const int pt0 = blockIdx.x * 8 + it * 4;

        // ===== LSE phase: lane = (point Q, neighbor r) =====
        {
            const int pt  = pt0 + Q;
            const int bb  = pt >> 15;
            const int nb  = nidx[pt0 * 16 + l];
            const int nbr = (bb << 15) + nb;

            const float cx = coords[pt * 3 + 0], cy = coords[pt * 3 + 1], cz = coords[pt * 3 + 2];
            const float rx = coords[nbr * 3 + 0] - cx;
            const float ry = coords[nbr * 3 + 1] - cy;
            const float rz = coords[nbr * 3 + 2] - cz;
            const float dd = sqrtf(rx * rx + ry * ry + rz * rz);
            float e4[4] = {rx, ry, rz, dd};

            float x24[24];
            {
                const float4* fp4 = (const float4*)(feats + nbr * 8);
                float4 f0 = fp4[0], f1 = fp4[1];
                x24[0] = f0.x; x24[1] = f0.y; x24[2] = f0.z; x24[3] = f0.w;
                x24[4] = f1.x; x24[5] = f1.y; x24[6] = f1.z; x24[7] = f1.w;
            }
            float h1[8];
            #pragma unroll
            for (int o = 0; o < 8; ++o) {
                float a = 0.f;
                #pragma unroll
                for (int i = 0; i < 4; ++i) a = fmaf(w1[o * 4 + i], e4[i], a);
                h1[o] = fmaxf(fmaf(a, g1[o] * BN_INV, b1[o]), 0.f);
            }
            #pragma unroll
            for (int o = 0; o < 16; ++o) {
                float a = 0.f;
                #pragma unroll
                for (int i = 0; i < 8; ++i) a = fmaf(w2[o * 8 + i], h1[i], a);
                x24[8 + o] = fmaxf(fmaf(a, g2[o] * BN_INV, b2[o]), 0.f);
            }
            uint4* row = (uint4*)&X1[Q * 648 + r * 40];
            row[0] = make_uint4(pk2(x24[0],  x24[1]),  pk2(x24[2],  x24[3]),
                                pk2(x24[4],  x24[5]),  pk2(x24[6],  x24[7]));
            row[1] = make_uint4(pk2(x24[8],  x24[9]),  pk2(x24[10], x24[11]),
                                pk2(x24[12], x24[13]), pk2(x24[14], x24[15]));
            row[2] = make_uint4(pk2(x24[16], x24[17]), pk2(x24[18], x24[19]),
                                pk2(x24[20], x24[21]), pk2(x24[22], x24[23]));
            row[3] = make_uint4(0u, 0u, 0u, 0u);
        }

        // ===== paired per-point MFMA chains (points 2pp, 2pp+1) =====
        const float4v z0 = {0.f, 0.f, 0.f, 0.f};
        #pragma unroll 1
        for (int pp = 0; pp < 2; ++pp) {
            ushort* X1A = X1 + (2 * pp) * 648;
            ushort* X1B = X1A + 648;
            const short8v a1A = *(const short8v*)&X1A[r * 40 + Q * 8];
            const short8v a1B = *(const short8v*)&X1B[r * 40 + Q * 8];
            const float4v d1aA = __builtin_amdgcn_mfma_f32_16x16x32_bf16(a1A, b1f0, z0, 0, 0, 0);
            const float4v d1bA = __builtin_amdgcn_mfma_f32_16x16x32_bf16(a1A, b1f1, z0, 0, 0, 0);
            const float4v d1aB = __builtin_amdgcn_mfma_f32_16x16x32_bf16(a1B, b1f0, z0, 0, 0, 0);
            const float4v d1bB = __builtin_amdgcn_mfma_f32_16x16x32_bf16(a1B, b1f1, z0, 0, 0, 0);
            #pragma unroll
            for (int q = 0; q < 4; ++q) {
                X2A[(4 * Q + q) * 40 + r]      = f2bf(fmaxf(fmaf(d1aA[q], sm1a, tm1a), 0.f));
                X2A[(4 * Q + q) * 40 + 16 + r] = f2bf(fmaxf(fmaf(d1bA[q], sm1b, tm1b), 0.f));
                X2B[(4 * Q + q) * 40 + r]      = f2bf(fmaxf(fmaf(d1aB[q], sm1a, tm1a), 0.f));
                X2B[(4 * Q + q) * 40 + 16 + r] = f2bf(fmaxf(fmaf(d1bB[q], sm1b, tm1b), 0.f));
            }
            const short8v a2A = *(const short8v*)&X2A[r * 40 + Q * 8];
            const short8v a2B = *(const short8v*)&X2B[r * 40 + Q * 8];
            float4v d2A[4], d2B[4];
            #pragma unroll
            for (int t = 0; t < 4; ++t) {
                d2A[t] = __builtin_amdgcn_mfma_f32_16x16x32_bf16(a2A, b2f[t], z0, 0, 0, 0);
                d2B[t] = __builtin_amdgcn_mfma_f32_16x16x32_bf16(a2B, b2f[t], z0, 0, 0, 0);
            }
            float xrA[4][4], xrB[4][4];
            #pragma unroll
            for (int t = 0; t < 4; ++t)
                #pragma unroll
                for (int q = 0; q < 4; ++q) {
                    xrA[t][q] = fmaxf(fmaf(d2A[t][q], sm2[t], tm2[t]), 0.f);
                    xrB[t][q] = fmaxf(fmaf(d2B[t][q], sm2[t], tm2[t]), 0.f);
                }

            // ---- fill both X3 tiles (X3B writes ordered after a2 reads) ----
            #pragma unroll
            for (int t = 0; t < 4; ++t)
                #pragma unroll
                for (int q = 0; q < 4; ++q) {
                    X3A[(4 * Q + q) * 76 + 16 * t + r] = f2bf(xrA[t][q]);
                    X3B[(4 * Q + q) * 72 + 16 * t + r] = f2bf(xrB[t][q]);
                }
            const short8v a3lA = *(const short8v*)&X3A[r * 76 + Q * 8];
            const short8v a3hA = *(const short8v*)&X3A[r * 76 + 32 + Q * 8];
            const short8v a3lB = *(const short8v*)&X3B[r * 72 + Q * 8];
            const short8v a3hB = *(const short8v*)&X3B[r * 72 + 32 + Q * 8];

            // ---- interleaved ATT + softmax for A and B ----
            float seA[4], snA[4], seB[4], snB[4];
            #pragma unroll
            for (int t = 0; t < 4; ++t) {
                float4v sA = __builtin_amdgcn_mfma_f32_16x16x32_bf16(a3lA, b3f[t * 2],     z0, 0, 0, 0);
                sA         = __builtin_amdgcn_mfma_f32_16x16x32_bf16(a3hA, b3f[t * 2 + 1], sA, 0, 0, 0);
                float4v sB = __builtin_amdgcn_mfma_f32_16x16x32_bf16(a3lB, b3f[t * 2],     z0, 0, 0, 0);
                sB         = __builtin_amdgcn_mfma_f32_16x16x32_bf16(a3hB, b3f[t * 2 + 1], sB, 0, 0, 0);
                float e0A = __expf(sA[0]), e1A = __expf(sA[1]);
                float e2A = __expf(sA[2]), e3A = __expf(sA[3]);
                float e0B = __expf(sB[0]), e1B = __expf(sB[1]);
                float e2B = __expf(sB[2]), e3B = __expf(sB[3]);
                seA[t] = (e0A + e1A) + (e2A + e3A);
                snA[t] = fmaf(e0A, xrA[t][0], e1A * xrA[t][1]) + fmaf(e2A, xrA[t][2], e3A * xrA[t][3]);
                seB[t] = (e0B + e1B) + (e2B + e3B);
                snB[t] = fmaf(e0B, xrB[t][0], e1B * xrB[t][1]) + fmaf(e2B, xrB[t][2], e3B * xrB[t][3]);
            }
            #pragma unroll
            for (int t = 0; t < 4; ++t) {
                seA[t] += __shfl_xor(seA[t], 16, 64);
                snA[t] += __shfl_xor(snA[t], 16, 64);
                seB[t] += __shfl_xor(seB[t], 16, 64);
                snB[t] += __shfl_xor(snB[t], 16, 64);
                seA[t] += __shfl_xor(seA[t], 32, 64);
                snA[t] += __shfl_xor(snA[t], 32, 64);
                seB[t] += __shfl_xor(seB[t], 32, 64);
                snB[t] += __shfl_xor(snB[t], 32, 64);
            }
            if (l < 16) {
                #pragma unroll
                for (int t = 0; t < 4; ++t) {
                    PL[(2 * pp) * 76 + 16 * t + l]     = f2bf(__fdividef(snA[t], seA[t]));
                    PL[(2 * pp + 1) * 76 + 16 * t + l] = f2bf(__fdividef(snB[t], seB[t]));
                }
            }
        }

        // ===== batched pool MFMA (fragments loaded fresh each wave-iter) =====
        short8v pbf[8];
        #pragma unroll
        for (int i = 0; i < 8; ++i) pbf[i] = FR[(14 + i) * 64 + l];
        float spv[4], tpv[4];
        #pragma unroll
        for (int t = 0; t < 4; ++t) {
            spv[t] = SC[(12 + t) * 64 + l]; tpv[t] = SC[(16 + t) * 64 + l];
        }
        const short8v apl0 = *(const short8v*)&PL[r * 76 + Q * 8];
        const short8v apl1 = *(const short8v*)&PL[r * 76 + 32 + Q * 8];
        float4v dp[4];
        #pragma unroll
        for (int t = 0; t < 4; ++t) {
            float4v d = __builtin_amdgcn_mfma_f32_16x16x32_bf16(apl0, pbf[t * 2],     z0, 0, 0, 0);
            d         = __builtin_amdgcn_mfma_f32_16x16x32_bf16(apl1, pbf[t * 2 + 1], d,  0, 0, 0);
            dp[t] = d;
        }
        if (l < 16) {
            #pragma unroll
            for (int q = 0; q < 4; ++q)
                #pragma unroll
                for (int t = 0; t < 4; ++t)
                    out[(pt0 + q) * 64 + 16 * t + l] =
                        fmaxf(fmaf(dp[t][q], spv[t], tpv[t]), 0.f);
        }
    }
}

extern "C" void kernel_launch(void* const* d_in, const int* in_sizes, int n_in,
                              void* d_out, int out_size, void* d_ws, size_t ws_size,
                              hipStream_t stream) {
    (void)in_sizes; (void)n_in; (void)ws_size; (void)out_size;
    const float* coords = (const float*)d_in[0];
    const float* feats  = (const float*)d_in[1];
    const int*   nidx   = (const int*)  d_in[2];
    const float* w1  = (const float*)d_in[3];
    const float* g1  = (const float*)d_in[4];
    const float* b1  = (const float*)d_in[5];
    const float* w2  = (const float*)d_in[6];
    const float* g2  = (const float*)d_in[7];
    const float* b2  = (const float*)d_in[8];
    const float* wm1 = (const float*)d_in[9];
    const float* gm1 = (const float*)d_in[10];
    const float* bm1 = (const float*)d_in[11];
    const float* wm2 = (const float*)d_in[12];
    const float* gm2 = (const float*)d_in[13];
    const float* bm2 = (const float*)d_in[14];
    const float* watt = (const float*)d_in[15];
    const float* wp  = (const float*)d_in[16];
    const float* gp  = (const float*)d_in[17];
    const float* bp  = (const float*)d_in[18];
    float* out = (float*)d_out;
    ushort* ws = (ushort*)d_ws;

    lfa_pack<<<dim3(11), dim3(256), 0, stream>>>(wm1, wm2, watt, wp,
                                                 gm1, bm1, gm2, bm2, gp, bp, ws);
    lfa_kernel<<<dim3(8192), dim3(64), 0, stream>>>(coords, feats, nidx,
                                                    w1, g1, b1, w2, g2, b2,
                                                    ws, out);
}

// Round 11
// 68.362 us; speedup vs baseline: 1.5224x; 1.0901x over previous
//
#include <hip/hip_runtime.h>
#include <hip/hip_bf16.h>

// LocalFeatureAggregation: B=2, N=32768, K=16, CIN=8, COUT=64
// MFMA version 7 = round-10 structure + (a) software-pipelined gather
// (prefetch next iter's nidx/coords/feats into regs during pair phase),
// (b) deferred pool: PL accumulates 16 points (4 iters) in its own LDS tile,
// ONE all-lane-valid pool MFMA epilogue per block.
// 1-wave blocks (64 thr), launch_bounds(64,2) (proven no-spill budget).
// Grid = 4096 blocks x 4 iters x 4 points.

typedef __attribute__((ext_vector_type(8))) short short8v;
typedef __attribute__((ext_vector_type(4))) float float4v;

#define BN_INV 0.9999950000374997f
#define NFRAG 22
#define NSCAL 20

// cheap float->bf16, round-half-up (1-ulp-on-ties vs RNE; inputs finite)
__device__ __forceinline__ ushort f2bf(float f) {
    return (ushort)((__float_as_uint(f) + 0x8000u) >> 16);
}
// pack two: low half = bf16(a), high half = bf16(b)   (2 add + 1 perm)
__device__ __forceinline__ uint pk2(float a, float b) {
    return __builtin_amdgcn_perm(__float_as_uint(b) + 0x8000u,
                                 __float_as_uint(a) + 0x8000u, 0x07060302u);
}

__device__ __forceinline__ ushort f2bf_rne(float f) {
    __hip_bfloat16 h = __float2bfloat16(f);
    return __builtin_bit_cast(ushort, h);
}

// ---- setup: pack per-lane MFMA B-fragments + scale/shift into d_ws ----
// layout: [NFRAG][64] x 16B fragments, then [NSCAL][64] x f32.
// frag order: 0 b1f0, 1 b1f1, 2-5 b2f[t], 6-13 b3f[2t+h], 14-21 pbf[2t+h].
__global__ __launch_bounds__(256)
void lfa_pack(const float* __restrict__ wm1, const float* __restrict__ wm2,
              const float* __restrict__ watt, const float* __restrict__ wp,
              const float* __restrict__ gm1, const float* __restrict__ bm1,
              const float* __restrict__ gm2, const float* __restrict__ bm2,
              const float* __restrict__ gp,  const float* __restrict__ bp,
              ushort* __restrict__ ws)
{
    const int t = blockIdx.x * 256 + threadIdx.x;
    if (t < NFRAG * 64) {
        const int f = t >> 6, l = t & 63, r = l & 15, Q = l >> 4;
        short8v v;
        #pragma unroll
        for (int j = 0; j < 8; ++j) {
            const int k = 8 * Q + j;
            float x;
            if (f == 0)      x = (k < 24) ? wm1[r * 24 + k] : 0.f;
            else if (f == 1) x = (k < 24) ? wm1[(16 + r) * 24 + k] : 0.f;
            else if (f < 6)  { int tt = f - 2;  x = wm2[(16 * tt + r) * 32 + k]; }
            else if (f < 14) { int i = f - 6,  tt = i >> 1, h = i & 1;
                               x = watt[(16 * tt + r) * 64 + 32 * h + k]; }
            else             { int i = f - 14, tt = i >> 1, h = i & 1;
                               x = wp[(16 * tt + r) * 64 + 32 * h + k]; }
            v[j] = (short)f2bf_rne(x);
        }
        ((short8v*)ws)[t] = v;
    } else if (t < NFRAG * 64 + NSCAL * 64) {
        const int i = t - NFRAG * 64;
        const int fld = i >> 6, l = i & 63, r = l & 15;
        float x;
        if (fld == 0)      x = gm1[r] * BN_INV;
        else if (fld == 1) x = bm1[r];
        else if (fld == 2) x = gm1[16 + r] * BN_INV;
        else if (fld == 3) x = bm1[16 + r];
        else if (fld < 8)  x = gm2[16 * (fld - 4) + r] * BN_INV;
        else if (fld < 12) x = bm2[16 * (fld - 8) + r];
        else if (fld < 16) x = gp[16 * (fld - 12) + r] * BN_INV;
        else               x = bp[16 * (fld - 16) + r];
        ((float*)(ws + NFRAG * 64 * 8))[i] = x;
    }
}

__global__ __launch_bounds__(64, 2)
void lfa_kernel(const float* __restrict__ coords,
                const float* __restrict__ feats,
                const int*   __restrict__ nidx,
                const float* __restrict__ w1, const float* __restrict__ g1, const float* __restrict__ b1,
                const float* __restrict__ w2, const float* __restrict__ g2, const float* __restrict__ b2,
                const ushort* __restrict__ fw,
                float* __restrict__ out)
{
    // one wave per block: X1 4pt x 16 rows x 40 ushorts (pt stride 648)
    //                     X2 2 tiles x 16 x 40 (X3B aliases this, stride 72)
    //                     X3 16 x 76 ; PL 16 rows x 76 (all 16 block points)
    __shared__ __align__(16) ushort sX1[2592];
    __shared__ __align__(16) ushort sX2[1280];
    __shared__ __align__(16) ushort sX3[1216];
    __shared__ __align__(16) ushort sPL[1216];   // 12608 B total

    const int l   = threadIdx.x & 63;
    const int r   = l & 15;
    const int Q   = l >> 4;
    const int ptb = blockIdx.x * 16;

    // ---- persistent fragments (b1/b2/b3; pool stuff loaded at epilogue) ----
    const short8v* FR = (const short8v*)fw;
    const float*   SC = (const float*)(fw + NFRAG * 64 * 8);
    const short8v b1f0 = FR[0 * 64 + l];
    const short8v b1f1 = FR[1 * 64 + l];
    short8v b2f[4], b3f[8];
    #pragma unroll
    for (int t = 0; t < 4; ++t) b2f[t] = FR[(2 + t) * 64 + l];
    #pragma unroll
    for (int i = 0; i < 8; ++i) b3f[i] = FR[(6 + i) * 64 + l];

    const float sm1a = SC[0 * 64 + l], tm1a = SC[1 * 64 + l];
    const float sm1b = SC[2 * 64 + l], tm1b = SC[3 * 64 + l];
    float sm2[4], tm2[4];
    #pragma unroll
    for (int t = 0; t < 4; ++t) {
        sm2[t] = SC[(4 + t) * 64 + l];  tm2[t] = SC[(8 + t) * 64 + l];
    }

    ushort* X1  = sX1;
    ushort* X2A = sX2;
    ushort* X2B = X2A + 640;
    ushort* X3A = sX3;
    ushort* X3B = X2A;            // 16 x 72, aliases dead X2A/X2B space

    // ---- prologue gather (it = 0): exposed once per block ----
    float cx, cy, cz, nx, ny, nz;
    float4 f0v, f1v;
    {
        const int pt0n = ptb;
        const int pt   = pt0n + Q;
        const int nb   = nidx[pt0n * 16 + l];
        const int bb   = pt >> 15;
        const int nbr  = (bb << 15) + nb;
        cx = coords[pt * 3 + 0];  cy = coords[pt * 3 + 1];  cz = coords[pt * 3 + 2];
        nx = coords[nbr * 3 + 0]; ny = coords[nbr * 3 + 1]; nz = coords[nbr * 3 + 2];
        const float4* fp4 = (const float4*)(feats + nbr * 8);
        f0v = fp4[0]; f1v = fp4[1];
    }

    #pragma unroll 1
    for (int it = 0; it < 4; ++it) {
        // ===== LSE phase from prefetched values: lane = (point Q, nbr r) =====
        {
            const float rx = nx - cx;
            const float ry = ny - cy;
            const float rz = nz - cz;
            const float dd = sqrtf(rx * rx + ry * ry + rz * rz);
            float e4[4] = {rx, ry, rz, dd};

            float x24[24];
            x24[0] = f0v.x; x24[1] = f0v.y; x24[2] = f0v.z; x24[3] = f0v.w;
            x24[4] = f1v.x; x24[5] = f1v.y; x24[6] = f1v.z; x24[7] = f1v.w;

            float h1[8];
            #pragma unroll
            for (int o = 0; o < 8; ++o) {
                float a = 0.f;
                #pragma unroll
                for (int i = 0; i < 4; ++i) a = fmaf(w1[o * 4 + i], e4[i], a);
                h1[o] = fmaxf(fmaf(a, g1[o] * BN_INV, b1[o]), 0.f);
            }
            #pragma unroll
            for (int o = 0; o < 16; ++o) {
                float a = 0.f;
                #pragma unroll
                for (int i = 0; i < 8; ++i) a = fmaf(w2[o * 8 + i], h1[i], a);
                x24[8 + o] = fmaxf(fmaf(a, g2[o] * BN_INV, b2[o]), 0.f);
            }
            uint4* row = (uint4*)&X1[Q * 648 + r * 40];
            row[0] = make_uint4(pk2(x24[0],  x24[1]),  pk2(x24[2],  x24[3]),
                                pk2(x24[4],  x24[5]),  pk2(x24[6],  x24[7]));
            row[1] = make_uint4(pk2(x24[8],  x24[9]),  pk2(x24[10], x24[11]),
                                pk2(x24[12], x24[13]), pk2(x24[14], x24[15]));
            row[2] = make_uint4(pk2(x24[16], x24[17]), pk2(x24[18], x24[19]),
                                pk2(x24[20], x24[21]), pk2(x24[22], x24[23]));
            row[3] = make_uint4(0u, 0u, 0u, 0u);
        }

        // ===== prefetch gather for it+1 (latency hidden under pair phase) =====
        if (it < 3) {
            const int pt0n = ptb + (it + 1) * 4;
            const int pt   = pt0n + Q;
            const int nb   = nidx[pt0n * 16 + l];
            const int bb   = pt >> 15;
            const int nbr  = (bb << 15) + nb;
            cx = coords[pt * 3 + 0];  cy = coords[pt * 3 + 1];  cz = coords[pt * 3 + 2];
            nx = coords[nbr * 3 + 0]; ny = coords[nbr * 3 + 1]; nz = coords[nbr * 3 + 2];
            const float4* fp4 = (const float4*)(feats + nbr * 8);
            f0v = fp4[0]; f1v = fp4[1];
        }

        // ===== paired per-point MFMA chains (points 2pp, 2pp+1) =====
        const float4v z0 = {0.f, 0.f, 0.f, 0.f};
        #pragma unroll 1
        for (int pp = 0; pp < 2; ++pp) {
            ushort* X1A = X1 + (2 * pp) * 648;
            ushort* X1B = X1A + 648;
            const short8v a1A = *(const short8v*)&X1A[r * 40 + Q * 8];
            const short8v a1B = *(const short8v*)&X1B[r * 40 + Q * 8];
            const float4v d1aA = __builtin_amdgcn_mfma_f32_16x16x32_bf16(a1A, b1f0, z0, 0, 0, 0);
            const float4v d1bA = __builtin_amdgcn_mfma_f32_16x16x32_bf16(a1A, b1f1, z0, 0, 0, 0);
            const float4v d1aB = __builtin_amdgcn_mfma_f32_16x16x32_bf16(a1B, b1f0, z0, 0, 0, 0);
            const float4v d1bB = __builtin_amdgcn_mfma_f32_16x16x32_bf16(a1B, b1f1, z0, 0, 0, 0);
            #pragma unroll
            for (int q = 0; q < 4; ++q) {
                X2A[(4 * Q + q) * 40 + r]      = f2bf(fmaxf(fmaf(d1aA[q], sm1a, tm1a), 0.f));
                X2A[(4 * Q + q) * 40 + 16 + r] = f2bf(fmaxf(fmaf(d1bA[q], sm1b, tm1b), 0.f));
                X2B[(4 * Q + q) * 40 + r]      = f2bf(fmaxf(fmaf(d1aB[q], sm1a, tm1a), 0.f));
                X2B[(4 * Q + q) * 40 + 16 + r] = f2bf(fmaxf(fmaf(d1bB[q], sm1b, tm1b), 0.f));
            }
            const short8v a2A = *(const short8v*)&X2A[r * 40 + Q * 8];
            const short8v a2B = *(const short8v*)&X2B[r * 40 + Q * 8];
            float4v d2A[4], d2B[4];
            #pragma unroll
            for (int t = 0; t < 4; ++t) {
                d2A[t] = __builtin_amdgcn_mfma_f32_16x16x32_bf16(a2A, b2f[t], z0, 0, 0, 0);
                d2B[t] = __builtin_amdgcn_mfma_f32_16x16x32_bf16(a2B, b2f[t], z0, 0, 0, 0);
            }
            float xrA[4][4], xrB[4][4];
            #pragma unroll
            for (int t = 0; t < 4; ++t)
                #pragma unroll
                for (int q = 0; q < 4; ++q) {
                    xrA[t][q] = fmaxf(fmaf(d2A[t][q], sm2[t], tm2[t]), 0.f);
                    xrB[t][q] = fmaxf(fmaf(d2B[t][q], sm2[t], tm2[t]), 0.f);
                }

            // ---- fill both X3 tiles (X3B writes ordered after a2 reads) ----
            #pragma unroll
            for (int t = 0; t < 4; ++t)
                #pragma unroll
                for (int q = 0; q < 4; ++q) {
                    X3A[(4 * Q + q) * 76 + 16 * t + r] = f2bf(xrA[t][q]);
                    X3B[(4 * Q + q) * 72 + 16 * t + r] = f2bf(xrB[t][q]);
                }
            const short8v a3lA = *(const short8v*)&X3A[r * 76 + Q * 8];
            const short8v a3hA = *(const short8v*)&X3A[r * 76 + 32 + Q * 8];
            const short8v a3lB = *(const short8v*)&X3B[r * 72 + Q * 8];
            const short8v a3hB = *(const short8v*)&X3B[r * 72 + 32 + Q * 8];

            // ---- interleaved ATT + softmax for A and B ----
            float seA[4], snA[4], seB[4], snB[4];
            #pragma unroll
            for (int t = 0; t < 4; ++t) {
                float4v sA = __builtin_amdgcn_mfma_f32_16x16x32_bf16(a3lA, b3f[t * 2],     z0, 0, 0, 0);
                sA         = __builtin_amdgcn_mfma_f32_16x16x32_bf16(a3hA, b3f[t * 2 + 1], sA, 0, 0, 0);
                float4v sB = __builtin_amdgcn_mfma_f32_16x16x32_bf16(a3lB, b3f[t * 2],     z0, 0, 0, 0);
                sB         = __builtin_amdgcn_mfma_f32_16x16x32_bf16(a3hB, b3f[t * 2 + 1], sB, 0, 0, 0);
                float e0A = __expf(sA[0]), e1A = __expf(sA[1]);
                float e2A = __expf(sA[2]), e3A = __expf(sA[3]);
                float e0B = __expf(sB[0]), e1B = __expf(sB[1]);
                float e2B = __expf(sB[2]), e3B = __expf(sB[3]);
                seA[t] = (e0A + e1A) + (e2A + e3A);
                snA[t] = fmaf(e0A, xrA[t][0], e1A * xrA[t][1]) + fmaf(e2A, xrA[t][2], e3A * xrA[t][3]);
                seB[t] = (e0B + e1B) + (e2B + e3B);
                snB[t] = fmaf(e0B, xrB[t][0], e1B * xrB[t][1]) + fmaf(e2B, xrB[t][2], e3B * xrB[t][3]);
            }
            #pragma unroll
            for (int t = 0; t < 4; ++t) {
                seA[t] += __shfl_xor(seA[t], 16, 64);
                snA[t] += __shfl_xor(snA[t], 16, 64);
                seB[t] += __shfl_xor(seB[t], 16, 64);
                snB[t] += __shfl_xor(snB[t], 16, 64);
                seA[t] += __shfl_xor(seA[t], 32, 64);
                snA[t] += __shfl_xor(snA[t], 32, 64);
                seB[t] += __shfl_xor(seB[t], 32, 64);
                snB[t] += __shfl_xor(snB[t], 32, 64);
            }
            if (l < 16) {
                #pragma unroll
                for (int t = 0; t < 4; ++t) {
                    sPL[(4 * it + 2 * pp) * 76 + 16 * t + l]     = f2bf(__fdividef(snA[t], seA[t]));
                    sPL[(4 * it + 2 * pp + 1) * 76 + 16 * t + l] = f2bf(__fdividef(snB[t], seB[t]));
                }
            }
        }
    }

    // ===== ONE pool MFMA epilogue for all 16 block points (all lanes valid) =====
    short8v pbf[8];
    #pragma unroll
    for (int i = 0; i < 8; ++i) pbf[i] = FR[(14 + i) * 64 + l];
    float spv[4], tpv[4];
    #pragma unroll
    for (int t = 0; t < 4; ++t) {
        spv[t] = SC[(12 + t) * 64 + l]; tpv[t] = SC[(16 + t) * 64 + l];
    }
    const float4v z0 = {0.f, 0.f, 0.f, 0.f};
    const short8v apl0 = *(const short8v*)&sPL[r * 76 + Q * 8];
    const short8v apl1 = *(const short8v*)&sPL[r * 76 + 32 + Q * 8];
    float4v dp[4];
    #pragma unroll
    for (int t = 0; t < 4; ++t) {
        float4v d = __builtin_amdgcn_mfma_f32_16x16x32_bf16(apl0, pbf[t * 2],     z0, 0, 0, 0);
        d         = __builtin_amdgcn_mfma_f32_16x16x32_bf16(apl1, pbf[t * 2 + 1], d,  0, 0, 0);
        dp[t] = d;
    }
    // D: row = 4Q+q = block point, col = 16t+r = output channel -> dense stores
    #pragma unroll
    for (int q = 0; q < 4; ++q)
        #pragma unroll
        for (int t = 0; t < 4; ++t)
            out[(ptb + 4 * Q + q) * 64 + 16 * t + r] =
                fmaxf(fmaf(dp[t][q], spv[t], tpv[t]), 0.f);
}

extern "C" void kernel_launch(void* const* d_in, const int* in_sizes, int n_in,
                              void* d_out, int out_size, void* d_ws, size_t ws_size,
                              hipStream_t stream) {
    (void)in_sizes; (void)n_in; (void)ws_size; (void)out_size;
    const float* coords = (const float*)d_in[0];
    const float* feats  = (const float*)d_in[1];
    const int*   nidx   = (const int*)  d_in[2];
    const float* w1  = (const float*)d_in[3];
    const float* g1  = (const float*)d_in[4];
    const float* b1  = (const float*)d_in[5];
    const float* w2  = (const float*)d_in[6];
    const float* g2  = (const float*)d_in[7];
    const float* b2  = (const float*)d_in[8];
    const float* wm1 = (const float*)d_in[9];
    const float* gm1 = (const float*)d_in[10];
    const float* bm1 = (const float*)d_in[11];
    const float* wm2 = (const float*)d_in[12];
    const float* gm2 = (const float*)d_in[13];
    const float* bm2 = (const float*)d_in[14];
    const float* watt = (const float*)d_in[15];
    const float* wp  = (const float*)d_in[16];
    const float* gp  = (const float*)d_in[17];
    const float* bp  = (const float*)d_in[18];
    float* out = (float*)d_out;
    ushort* ws = (ushort*)d_ws;

    lfa_pack<<<dim3(11), dim3(256), 0, stream>>>(wm1, wm2, watt, wp,
                                                 gm1, bm1, gm2, bm2, gp, bp, ws);
    lfa_kernel<<<dim3(4096), dim3(64), 0, stream>>>(coords, feats, nidx,
                                                    w1, g1, b1, w2, g2, b2,
                                                    ws, out);
}